// Round 10
// baseline (254.818 us; speedup 1.0000x reference)
//
#include <hip/hip_runtime.h>
#include <hip/hip_bf16.h>

#define IN_FEAT 128
#define N_HEADS 4
#define OUT_FEAT 16
#define HF 64  // N_HEADS * OUT_FEAT
#define NEG_SLOPE 0.2f
#define NRANGE 8   // dst-space buckets ~ XCD count

typedef __hip_bfloat16 bf16;
typedef __attribute__((ext_vector_type(8))) short short8;
typedef __attribute__((ext_vector_type(4))) float f32x4;
typedef __attribute__((ext_vector_type(4))) int i32x4;
typedef __attribute__((ext_vector_type(4))) float fltx4;

template <typename T>
__device__ inline T ntl(const T* p) { return __builtin_nontemporal_load(p); }

__device__ inline unsigned short f2b(float f) {
  bf16 b = __float2bfloat16(f);
  return *(unsigned short*)&b;
}
__device__ inline float b2f(unsigned short u) {
  return __uint_as_float((unsigned)u << 16);
}

// ---------------------------------------------------------------------------
// Prep: build Wt (bf16 W^T, 16 KB) + zero counts. One dispatch, 32 blocks.
// ---------------------------------------------------------------------------
__global__ __launch_bounds__(256) void k_prep(
    const float* __restrict__ W, unsigned short* __restrict__ Wt,
    int* __restrict__ counts, int n_nodes) {
  int i = blockIdx.x * 256 + threadIdx.x;   // 8192 threads
  int k = i >> 6, c = i & 63;
  Wt[c * IN_FEAT + k] = f2b(W[i]);
  for (int j = i; j < n_nodes + 1; j += 8192) counts[j] = 0;
}

// ---------------------------------------------------------------------------
// Kernel 1: h = x @ W via bf16 MFMA (256 thr = 4 waves = 64 nodes) +
// FUSED histogram that also records rank[e] = arrival order within dst
// segment (the atomic's return value) — removes the atomic from k_reorder.
// ---------------------------------------------------------------------------
__global__ __launch_bounds__(256) void k_gemm(
    const float* __restrict__ x, const unsigned short* __restrict__ Wt,
    const float* __restrict__ a, unsigned short* __restrict__ h16,
    float* __restrict__ e_src, float* __restrict__ e_dst,
    const int* __restrict__ dst, int* __restrict__ counts,
    int* __restrict__ rank, int n_nodes, int n_edges) {
  __shared__ unsigned short xs[64][136];
  __shared__ unsigned short sh[64][68];
  const int t = threadIdx.x;
  const int nb = blockIdx.x * 64;
  const int lane = t & 63;
  const int w = t >> 6;

  const fltx4* x4 = (const fltx4*)x;
  for (int i = t; i < 64 * 32; i += 256) {
    int n = i >> 5, k4 = i & 31;
    int gn = nb + n;
    fltx4 v = (gn < n_nodes) ? ntl(&x4[(size_t)gn * 32 + k4])
                             : (fltx4){0.f, 0.f, 0.f, 0.f};
    ushort4 u;
    u.x = f2b(v[0]); u.y = f2b(v[1]); u.z = f2b(v[2]); u.w = f2b(v[3]);
    *(ushort4*)&xs[n][k4 * 4] = u;
  }
  __syncthreads();

  const int m = lane & 15;
  const int q = lane >> 4;
  f32x4 acc[4];
#pragma unroll
  for (int nt = 0; nt < 4; ++nt) acc[nt] = (f32x4){0.f, 0.f, 0.f, 0.f};

#pragma unroll
  for (int kc = 0; kc < 4; ++kc) {
    short8 af = *(const short8*)&xs[w * 16 + m][kc * 32 + q * 8];
#pragma unroll
    for (int nt = 0; nt < 4; ++nt) {
      short8 bfr = *(const short8*)&Wt[(nt * 16 + m) * IN_FEAT + kc * 32 + q * 8];
      acc[nt] = __builtin_amdgcn_mfma_f32_16x16x32_bf16(af, bfr, acc[nt], 0, 0, 0);
    }
  }

#pragma unroll
  for (int nt = 0; nt < 4; ++nt)
#pragma unroll
    for (int r = 0; r < 4; ++r)
      sh[w * 16 + q * 4 + r][nt * 16 + m] = f2b(acc[nt][r]);
  __syncthreads();

  {
    int n = t >> 2, hd = t & 3;
    int gn = nb + n;
    if (gn < n_nodes) {
      float es = 0.f, ed = 0.f;
#pragma unroll
      for (int f = 0; f < OUT_FEAT; ++f) {
        float hv = b2f(sh[n][hd * 16 + f]);
        es = fmaf(hv, a[hd * 2 * OUT_FEAT + f], es);
        ed = fmaf(hv, a[hd * 2 * OUT_FEAT + OUT_FEAT + f], ed);
      }
      e_src[gn * N_HEADS + hd] = es;
      e_dst[gn * N_HEADS + hd] = ed;
    }
  }

  for (int i = t; i < 64 * 16; i += 256) {
    int n = i >> 4, c4 = (i & 15) * 4;
    int gn = nb + n;
    if (gn < n_nodes) {
      ushort4 v;
      v.x = sh[n][c4 + 0]; v.y = sh[n][c4 + 1];
      v.z = sh[n][c4 + 2]; v.w = sh[n][c4 + 3];
      *(ushort4*)(h16 + (size_t)gn * HF + c4) = v;
    }
  }

  // Fused histogram with rank capture: grid-stride, coalesced rank writes.
  const int stride = gridDim.x * 256;
  for (int e = blockIdx.x * 256 + t; e < n_edges; e += stride) {
    int d = ntl(&dst[e]);
    rank[e] = atomicAdd(&counts[d], 1);
  }
}

// ---------------------------------------------------------------------------
// Single-block scan, COALESCED tiles (fixes round-5's 196B-stride mistake):
// 49 tiles of 1024 contiguous elements; intra-wave __shfl_up scan (no
// barriers), 16 wave-sums scanned by wave 0, running total carried in LDS.
// ---------------------------------------------------------------------------
__global__ __launch_bounds__(1024) void k_scan(
    const int* __restrict__ counts, int* __restrict__ offsets,
    int n, int n_edges) {
  __shared__ int swave[17];
  const int t = threadIdx.x;
  const int lane = t & 63;
  const int wid = t >> 6;
  const int ntiles = (n + 1023) / 1024;
  int running = 0;
  for (int tile = 0; tile < ntiles; ++tile) {
    int idx = tile * 1024 + t;
    int v0 = (idx < n) ? counts[idx] : 0;
    int v = v0;
#pragma unroll
    for (int off = 1; off < 64; off <<= 1) {
      int u = __shfl_up(v, off);
      if (lane >= off) v += u;
    }
    if (lane == 63) swave[wid] = v;   // wave inclusive sums
    __syncthreads();
    if (wid == 0) {
      int v2 = (lane < 16) ? swave[lane] : 0;
#pragma unroll
      for (int off = 1; off < 16; off <<= 1) {
        int u2 = __shfl_up(v2, off);
        if (lane >= off) v2 += u2;
      }
      if (lane < 16) swave[lane] = v2;          // inclusive scan of wave sums
      if (lane == 15) swave[16] = v2;           // tile total
    }
    __syncthreads();
    int wexcl = (wid == 0) ? 0 : swave[wid - 1];
    if (idx < n) offsets[idx] = running + wexcl + (v - v0);
    running += swave[16];
    __syncthreads();  // protect swave before next tile overwrites
  }
  if (t == 0) offsets[n] = n_edges;
}

// ---------------------------------------------------------------------------
// Reorder + softmax, ATOMIC-FREE: pos = offsets[d] + rank[e].
// XCD-bucketed (blockIdx%8 ~ XCD) for rec-line write combining.
// 8 edges per thread, all gathers hoisted -> deep MLP, no dependent atomics.
// ---------------------------------------------------------------------------
__global__ __launch_bounds__(256) void k_reorder(
    const int* __restrict__ src, const int* __restrict__ dst,
    const int* __restrict__ rank, const int* __restrict__ offsets,
    const float* __restrict__ e_src, const float* __restrict__ e_dst,
    unsigned long long* __restrict__ recs, int n_edges, int rsize) {
  const int range = blockIdx.x & (NRANGE - 1);
  const int chunk = blockIdx.x >> 3;
  const int lo = range * rsize;
  const int base = chunk * 2048 + threadIdx.x * 8;

  int ds[8], ss[8], rk[8];
  if (base + 8 <= n_edges) {
    i32x4 d0 = ntl((const i32x4*)&dst[base]);
    i32x4 d1 = ntl((const i32x4*)&dst[base + 4]);
    i32x4 s0 = ntl((const i32x4*)&src[base]);
    i32x4 s1 = ntl((const i32x4*)&src[base + 4]);
    i32x4 r0 = ntl((const i32x4*)&rank[base]);
    i32x4 r1 = ntl((const i32x4*)&rank[base + 4]);
#pragma unroll
    for (int k = 0; k < 4; ++k) {
      ds[k] = d0[k]; ds[k + 4] = d1[k];
      ss[k] = s0[k]; ss[k + 4] = s1[k];
      rk[k] = r0[k]; rk[k + 4] = r1[k];
    }
  } else {
    for (int k = 0; k < 8; ++k) {
      int e = base + k;
      ds[k] = (e < n_edges) ? dst[e] : -1;
      ss[k] = (e < n_edges) ? src[e] : 0;
      rk[k] = (e < n_edges) ? rank[e] : 0;
    }
  }

  bool act[8];
  float4 es[8], ed[8];
  int pos[8];
#pragma unroll
  for (int k = 0; k < 8; ++k)
    act[k] = ((unsigned)(ds[k] - lo) < (unsigned)rsize);
  // Hoist all gathers (independent loads -> overlapped latency).
#pragma unroll
  for (int k = 0; k < 8; ++k)
    if (act[k]) {
      es[k] = ((const float4*)e_src)[ss[k]];
      ed[k] = ((const float4*)e_dst)[ds[k]];
      pos[k] = offsets[ds[k]] + rk[k];
    }
#pragma unroll
  for (int k = 0; k < 8; ++k) {
    if (!act[k]) continue;
    float v0 = es[k].x + ed[k].x, v1 = es[k].y + ed[k].y;
    float v2 = es[k].z + ed[k].z, v3 = es[k].w + ed[k].w;
    v0 = (v0 > 0.f) ? v0 : NEG_SLOPE * v0;
    v1 = (v1 > 0.f) ? v1 : NEG_SLOPE * v1;
    v2 = (v2 > 0.f) ? v2 : NEG_SLOPE * v2;
    v3 = (v3 > 0.f) ? v3 : NEG_SLOPE * v3;
    float m = fmaxf(fmaxf(v0, v1), fmaxf(v2, v3));
    float e0 = __expf(v0 - m), e1 = __expf(v1 - m);
    float e2 = __expf(v2 - m), e3 = __expf(v3 - m);
    float inv = 255.f / (e0 + e1 + e2 + e3);
    unsigned p0 = (unsigned)(e0 * inv + 0.5f);
    unsigned p1 = (unsigned)(e1 * inv + 0.5f);
    unsigned p2 = (unsigned)(e2 * inv + 0.5f);
    unsigned p3 = (unsigned)(e3 * inv + 0.5f);
    unsigned a8 = p0 | (p1 << 8) | (p2 << 16) | (p3 << 24);
    recs[pos[k]] =
        (unsigned long long)(unsigned)ss[k] | ((unsigned long long)a8 << 32);
  }
}

// ---------------------------------------------------------------------------
// Gather: one wave per dst node, lane = feature. 8B recs, u8 alpha. x8.
// ---------------------------------------------------------------------------
__global__ __launch_bounds__(256) void k_gather(
    const unsigned long long* __restrict__ recs,
    const int* __restrict__ offsets, const unsigned short* __restrict__ h16,
    float* __restrict__ out, int n_nodes) {
  int gid = blockIdx.x * 256 + threadIdx.x;
  int d = gid >> 6;
  int c = gid & 63;
  if (d >= n_nodes) return;
  int beg = offsets[d];
  int end = offsets[d + 1];
  const unsigned shamt = (unsigned)(c >> 4) * 8;
  const float ascale = 1.f / 255.f;
  float acc = 0.f;
  int j = beg;
  for (; j + 8 <= end; j += 8) {
    unsigned long long r[8];
    float hv[8];
#pragma unroll
    for (int k = 0; k < 8; ++k) r[k] = ntl(&recs[j + k]);
#pragma unroll
    for (int k = 0; k < 8; ++k)
      hv[k] = b2f(h16[(size_t)(unsigned)(r[k] & 0xFFFFFFFFu) * HF + c]);
#pragma unroll
    for (int k = 0; k < 8; ++k) {
      unsigned a8 = (unsigned)(r[k] >> 32);
      float al = (float)((a8 >> shamt) & 0xFFu) * ascale;
      acc = fmaf(al, hv[k], acc);
    }
  }
  for (; j < end; ++j) {
    unsigned long long r = ntl(&recs[j]);
    float hv = b2f(h16[(size_t)(unsigned)(r & 0xFFFFFFFFu) * HF + c]);
    unsigned a8 = (unsigned)(r >> 32);
    float al = (float)((a8 >> shamt) & 0xFFu) * ascale;
    acc = fmaf(al, hv, acc);
  }
  __builtin_nontemporal_store(acc, &out[(size_t)d * HF + c]);
}

extern "C" void kernel_launch(void* const* d_in, const int* in_sizes, int n_in,
                              void* d_out, int out_size, void* d_ws, size_t ws_size,
                              hipStream_t stream) {
  const float* x = (const float*)d_in[0];
  const int* ei = (const int*)d_in[1];
  const float* W = (const float*)d_in[2];
  const float* a = (const float*)d_in[3];
  float* out = (float*)d_out;

  const int n_nodes = in_sizes[0] / IN_FEAT;   // 50000
  const int n_edges = in_sizes[1] / 2;         // 800000
  const int* src = ei;
  const int* dst = ei + n_edges;

  char* ws = (char*)d_ws;
  size_t off = 0;
  unsigned short* h16 = (unsigned short*)(ws + off); off += (size_t)n_nodes * HF * 2;  // 6.4 MB
  unsigned long long* recs = (unsigned long long*)(ws + off); off += (size_t)n_edges * 8; // 6.4 MB
  float* e_src = (float*)(ws + off);      off += (size_t)n_nodes * N_HEADS * 4;        // 0.8 MB
  float* e_dst = (float*)(ws + off);      off += (size_t)n_nodes * N_HEADS * 4;        // 0.8 MB
  int* rank = (int*)(ws + off);           off += (size_t)n_edges * 4;                  // 3.2 MB
  unsigned short* Wt = (unsigned short*)(ws + off); off += (size_t)IN_FEAT * HF * 2;   // 16 KB
  int* counts = (int*)(ws + off);         off += ((size_t)n_nodes + 16) * 4;
  int* offsets = (int*)(ws + off);        off += ((size_t)n_nodes + 16) * 4;

  const int rsize = (n_nodes + NRANGE - 1) / NRANGE;  // 6250
  const int n_chunks = (n_edges + 2047) / 2048;       // 391
  const int nb_bucketed = n_chunks * NRANGE;          // 3128 blocks

  k_prep<<<32, 256, 0, stream>>>(W, Wt, counts, n_nodes);
  k_gemm<<<(n_nodes + 63) / 64, 256, 0, stream>>>(
      x, Wt, a, h16, e_src, e_dst, dst, counts, rank, n_nodes, n_edges);
  k_scan<<<1, 1024, 0, stream>>>(counts, offsets, n_nodes, n_edges);
  k_reorder<<<nb_bucketed, 256, 0, stream>>>(
      src, dst, rank, offsets, e_src, e_dst, recs, n_edges, rsize);
  k_gather<<<(n_nodes * 64 + 255) / 256, 256, 0, stream>>>(
      recs, offsets, h16, out, n_nodes);
}